// Round 1
// baseline (27.744 us; speedup 1.0000x reference)
//
#include <hip/hip_runtime.h>

// LengthRegulator LR path:
//   x: [B, T_IN, H] fp32, duration: [B, T_MEL] int (0 => zero frame, 1..T_IN => x[d-1])
//   out0: [B, T_MEL, H] fp32 gather;  out1: mel_len[B] = first zero index else T_MEL (as fp32)
// B=16, T_IN=512, H=256, T_MEL=4096

#define H_DIM 256
#define T_IN  512

// One 64-lane group per output row; each lane copies one float4 (16B).
// 256 threads/block = 4 rows/block.
__global__ void lr_gather_kernel(const float* __restrict__ x,
                                 const int* __restrict__ dur,
                                 float* __restrict__ out,
                                 int rows, int t_mel_log2) {
    const int row  = blockIdx.x * 4 + (threadIdx.x >> 6);
    const int lane = threadIdx.x & 63;
    if (row >= rows) return;
    const int b = row >> t_mel_log2;           // t_mel is a power of two (4096)
    const int d = dur[row];                    // 64 lanes same addr -> broadcast
    float4 v = make_float4(0.f, 0.f, 0.f, 0.f);
    if (d != 0) {
        const float4* src = reinterpret_cast<const float4*>(
            x + ((size_t)b * T_IN + (size_t)(d - 1)) * H_DIM);
        v = src[lane];
    }
    reinterpret_cast<float4*>(out + (size_t)row * H_DIM)[lane] = v;
}

// One block per batch row: min index t where dur[b,t]==0, else t_mel.
__global__ void lr_mellen_kernel(const int* __restrict__ dur,
                                 float* __restrict__ mel_out,
                                 int t_mel) {
    const int b = blockIdx.x;
    const int* row = dur + (size_t)b * t_mel;
    int m = t_mel;
    for (int t = threadIdx.x; t < t_mel; t += blockDim.x) {
        int d = row[t];
        if (d == 0 && t < m) m = t;
    }
    // wave-64 butterfly min
    for (int off = 32; off > 0; off >>= 1)
        m = min(m, __shfl_down(m, off, 64));
    __shared__ int sm[4];
    const int wid = threadIdx.x >> 6;
    if ((threadIdx.x & 63) == 0) sm[wid] = m;
    __syncthreads();
    if (threadIdx.x == 0) {
        int r = sm[0];
        const int nw = (int)(blockDim.x >> 6);
        for (int w = 1; w < nw; ++w) r = min(r, sm[w]);
        mel_out[b] = (float)r;
    }
}

extern "C" void kernel_launch(void* const* d_in, const int* in_sizes, int n_in,
                              void* d_out, int out_size, void* d_ws, size_t ws_size,
                              hipStream_t stream) {
    const float* x   = (const float*)d_in[0];
    const int*   dur = (const int*)d_in[1];
    float* out = (float*)d_out;

    const int t_mel = 4096;
    const int n_dur = in_sizes[1];          // B * T_MEL
    const int B     = n_dur / t_mel;        // 16
    const int rows  = n_dur;                // B * T_MEL = 65536

    float* mel_out = out + (size_t)rows * H_DIM;  // tail: B fp32 values

    dim3 block(256);
    dim3 grid((rows + 3) / 4);
    lr_gather_kernel<<<grid, block, 0, stream>>>(x, dur, out, rows, 12 /*log2(4096)*/);
    lr_mellen_kernel<<<B, 256, 0, stream>>>(dur, mel_out, t_mel);
}

// Round 2
// 25.150 us; speedup vs baseline: 1.1031x; 1.1031x over previous
//
#include <hip/hip_runtime.h>

// LengthRegulator LR path:
//   x: [B, T_IN, H] fp32, duration: [B, T_MEL] int (0 => zero frame, 1..T_IN => x[d-1])
//   out0: [B, T_MEL, H] fp32 gather;  out1: mel_len[B] = first zero index else T_MEL (as fp32)
// B=16, T_IN=512, H=256, T_MEL=4096

#define H_DIM 256
#define T_IN  512
#define T_MEL_LOG2 12

// Grid-stride over flat float4 elements of out (rows * 64 per row).
// Consecutive threads -> consecutive float4 -> fully coalesced stores.
// Each 64-thread group shares one dur[row] (single broadcast transaction).
// 2048 blocks x 256 threads, ~8 iterations/thread => ILP for latency hiding.
__global__ void lr_gather_kernel(const float* __restrict__ x,
                                 const int* __restrict__ dur,
                                 float* __restrict__ out,
                                 long long n_vec4) {
    const long long stride = (long long)gridDim.x * blockDim.x;
    float4* __restrict__ o4 = reinterpret_cast<float4*>(out);
    for (long long f = (long long)blockIdx.x * blockDim.x + threadIdx.x;
         f < n_vec4; f += stride) {
        const long long row  = f >> 6;          // 64 float4 per row
        const int       lane = (int)(f & 63);
        const int b = (int)(row >> T_MEL_LOG2);
        const int d = dur[row];
        float4 v = make_float4(0.f, 0.f, 0.f, 0.f);
        if (d != 0) {
            v = reinterpret_cast<const float4*>(
                    x + ((size_t)b * T_IN + (size_t)(d - 1)) * H_DIM)[lane];
        }
        o4[f] = v;
    }
}

// One block per batch row: min index t where dur[b,t]==0, else t_mel.
// int4 loads: 4096/4 = 1024 vec-elems, 256 threads -> 4 iterations.
__global__ void lr_mellen_kernel(const int* __restrict__ dur,
                                 float* __restrict__ mel_out,
                                 int t_mel) {
    const int b = blockIdx.x;
    const int4* row = reinterpret_cast<const int4*>(dur + (size_t)b * t_mel);
    const int nv = t_mel >> 2;
    int m = t_mel;
    for (int i = threadIdx.x; i < nv; i += blockDim.x) {
        int4 d = row[i];
        int t = i << 2;
        if (d.x == 0 && t + 0 < m) m = t + 0;
        if (d.y == 0 && t + 1 < m) m = t + 1;
        if (d.z == 0 && t + 2 < m) m = t + 2;
        if (d.w == 0 && t + 3 < m) m = t + 3;
    }
    // wave-64 butterfly min
    for (int off = 32; off > 0; off >>= 1)
        m = min(m, __shfl_down(m, off, 64));
    __shared__ int sm[16];
    const int wid = threadIdx.x >> 6;
    if ((threadIdx.x & 63) == 0) sm[wid] = m;
    __syncthreads();
    if (threadIdx.x == 0) {
        int r = sm[0];
        const int nw = (int)(blockDim.x >> 6);
        for (int w = 1; w < nw; ++w) r = min(r, sm[w]);
        mel_out[b] = (float)r;
    }
}

extern "C" void kernel_launch(void* const* d_in, const int* in_sizes, int n_in,
                              void* d_out, int out_size, void* d_ws, size_t ws_size,
                              hipStream_t stream) {
    const float* x   = (const float*)d_in[0];
    const int*   dur = (const int*)d_in[1];
    float* out = (float*)d_out;

    const int t_mel = 4096;
    const int n_dur = in_sizes[1];          // B * T_MEL
    const int B     = n_dur / t_mel;        // 16
    const long long rows = n_dur;           // 65536
    const long long n_vec4 = rows * (H_DIM / 4);  // 4.19M float4

    float* mel_out = out + (size_t)rows * H_DIM;  // tail: B fp32 values

    lr_gather_kernel<<<2048, 256, 0, stream>>>(x, dur, out, n_vec4);
    lr_mellen_kernel<<<B, 256, 0, stream>>>(dur, mel_out, t_mel);
}

// Round 3
// 17.766 us; speedup vs baseline: 1.5616x; 1.4156x over previous
//
#include <hip/hip_runtime.h>

// LengthRegulator LR path (fused single kernel):
//   x: [B, T_IN, H] fp32, duration: [B, T_MEL] int (0 => zero frame, 1..T_IN => x[d-1])
//   out0: [B, T_MEL, H] fp32 gather;  out1: mel_len[B] = first zero index else T_MEL (fp32)
// B=16, T_IN=512, H=256, T_MEL=4096

#define H_DIM 256
#define T_IN  512
#define T_MEL 4096
#define T_MEL_LOG2 12
#define TPB 256
#define F4_PER_BLOCK 2048   // 8 iters * 256 threads * 1 float4

typedef float f32x4 __attribute__((ext_vector_type(4)));

__global__ __launch_bounds__(TPB) void lr_fused_kernel(
    const float* __restrict__ x, const int* __restrict__ dur,
    float* __restrict__ out, float* __restrict__ mel_out,
    int nB, int nblk) {

    // ---- fused mel_len: blocks 0..nB-1 scan their batch's 16 KB dur row ----
    if ((int)blockIdx.x < nB) {
        const int b = blockIdx.x;
        const int4* row = reinterpret_cast<const int4*>(dur + (size_t)b * T_MEL);
        int m = T_MEL;
        #pragma unroll
        for (int i = 0; i < T_MEL / 4 / TPB; ++i) {
            const int idx = i * TPB + threadIdx.x;
            const int4 dv = row[idx];
            const int t = idx << 2;
            if (dv.x == 0) m = min(m, t);
            if (dv.y == 0) m = min(m, t + 1);
            if (dv.z == 0) m = min(m, t + 2);
            if (dv.w == 0) m = min(m, t + 3);
        }
        for (int off = 32; off > 0; off >>= 1)
            m = min(m, __shfl_down(m, off, 64));
        __shared__ int sm[TPB / 64];
        if ((threadIdx.x & 63) == 0) sm[threadIdx.x >> 6] = m;
        __syncthreads();
        if (threadIdx.x == 0)
            mel_out[b] = (float)min(min(sm[0], sm[1]), min(sm[2], sm[3]));
    }

    // ---- gather: XCD-chunked so each XCD's x working set is ~2 MiB (L2-fit) ----
    // nblk % 8 == 0 -> bijective swizzle
    const int eff = ((int)blockIdx.x & 7) * (nblk >> 3) + ((int)blockIdx.x >> 3);
    const long long base = (long long)eff * F4_PER_BLOCK + threadIdx.x;

    // batch all 8 dur loads (independent; broadcast within each 64-lane group)
    int d[8];
    #pragma unroll
    for (int i = 0; i < 8; ++i)
        d[i] = dur[(base + (long long)i * TPB) >> 6];

    // branchless x loads (d==0 -> load row 0, select zero after; 0.2% waste)
    f32x4 v[8];
    #pragma unroll
    for (int i = 0; i < 8; ++i) {
        const long long f = base + (long long)i * TPB;
        const int lane = (int)(f & 63);
        const int brow = (int)(f >> 6);
        const int b = brow >> T_MEL_LOG2;
        const int dd = d[i] ? d[i] - 1 : 0;
        const f32x4 t = *reinterpret_cast<const f32x4*>(
            x + ((size_t)b * T_IN + (size_t)dd) * H_DIM + lane * 4);
        const f32x4 z = {0.f, 0.f, 0.f, 0.f};
        v[i] = d[i] ? t : z;
    }

    // nontemporal stores: write stream bypasses L2 allocation, keeps x resident
    f32x4* o4 = reinterpret_cast<f32x4*>(out);
    #pragma unroll
    for (int i = 0; i < 8; ++i)
        __builtin_nontemporal_store(v[i], &o4[base + (long long)i * TPB]);
}

extern "C" void kernel_launch(void* const* d_in, const int* in_sizes, int n_in,
                              void* d_out, int out_size, void* d_ws, size_t ws_size,
                              hipStream_t stream) {
    const float* x   = (const float*)d_in[0];
    const int*   dur = (const int*)d_in[1];
    float* out = (float*)d_out;

    const int n_dur = in_sizes[1];                 // B * T_MEL
    const int B     = n_dur / T_MEL;               // 16
    const long long rows   = n_dur;                // 65536
    const long long n_vec4 = rows * (H_DIM / 4);   // 4,194,304 float4
    const int nblk = (int)(n_vec4 / F4_PER_BLOCK); // 2048 (exact)

    float* mel_out = out + (size_t)rows * H_DIM;   // tail: B fp32 values

    lr_fused_kernel<<<nblk, TPB, 0, stream>>>(x, dur, out, mel_out, B, nblk);
}